// Round 12
// baseline (193.538 us; speedup 1.0000x reference)
//
#include <hip/hip_runtime.h>
#include <hip/hip_bf16.h>

#define NN 768
#define MD 1024
#define NPAIR 295296            // 768*769/2
#define NPBLK2 2307             // NPAIR / 128 (exact)

typedef __attribute__((ext_vector_type(8))) short s16x8;
typedef __attribute__((ext_vector_type(4))) float f32x4;
typedef __attribute__((ext_vector_type(2))) float f32x2;
typedef __attribute__((ext_vector_type(2))) __bf16 b16x2;

__device__ __forceinline__ ushort bf16_rn(float f) {
    uint u = __builtin_bit_cast(uint, f);
    u += 0x7FFFu + ((u >> 16) & 1u);
    return (ushort)(u >> 16);
}

// inverse triangular index (fallback kernel only)
__device__ __forceinline__ void ptoij(int p, int& io, int& jo) {
    const float disc = (float)(1537 * 1537 - 8 * p);
    int i = (int)((1537.0f - sqrtf(disc)) * 0.5f);
    i = i < 0 ? 0 : (i > 767 ? 767 : i);
    while (i > 0 && p < i * (1537 - i) / 2) --i;
    while (i < 767 && p >= (i + 1) * (1536 - i) / 2) ++i;
    io = i;
    jo = i + (p - i * (1537 - i) / 2);
}

#define GLOAD16(gsrc, ldst)                                                        \
    __builtin_amdgcn_global_load_lds(                                              \
        (const __attribute__((address_space(1))) void*)(gsrc),                     \
        (__attribute__((address_space(3))) void*)(ldst), 16, 0, 0)

// ---------- one-time: W2 -> bf16 (RNE), chunk-major + XOR-swizzled -------------
// chunk c (m0=c*64): 128 rows(k) x 128B; byte-in-row = (mg*16) ^ ((k&7)<<4)
__global__ __launch_bounds__(256) void w2bf16(const float* __restrict__ W2,
                                              ushort* __restrict__ WhiS)
{
    const int id = blockIdx.x * 256 + threadIdx.x;
    const int k = id >> 7;
    const int m = (id & 127) * 8;
    const float4 a = *reinterpret_cast<const float4*>(W2 + k * MD + m);
    const float4 b = *reinterpret_cast<const float4*>(W2 + k * MD + m + 4);
    const float w[8] = {a.x, a.y, a.z, a.w, b.x, b.y, b.z, b.w};
    s16x8 h;
#pragma unroll
    for (int e = 0; e < 8; ++e) h[e] = (short)bf16_rn(w[e]);
    const int c = m >> 6;
    const int mg = (m >> 3) & 7;
    const int byte = (mg * 16) ^ ((k & 7) << 4);
    const int off = c * 8192 + ((k * 128 + byte) >> 1);
    *reinterpret_cast<s16x8*>(&WhiS[off]) = h;
}

// ---------- one-time: EA f32 row-major + ECs bf16 staged layout ----------------
// EA[r][m] = 2^(-(a_m x_r + b_m) log2e);  EC factor = 2^(-c_m x_r log2e)
// ECs chunk c: [768 r][64 m bf16 = 128B row], byte = (mg*16) ^ ((r&7)<<4)
__global__ __launch_bounds__(256) void etab2(const float* __restrict__ x,
                                             const float* __restrict__ W1,
                                             const float* __restrict__ b1,
                                             float* __restrict__ EA,
                                             ushort* __restrict__ ECs)
{
    const int r = blockIdx.x;
    const float xr = x[r];
    const float NL2E = -1.4426950408889634f;
    for (int m = threadIdx.x; m < MD; m += 256) {
        const float2 w = reinterpret_cast<const float2*>(W1)[m];
        EA[r * MD + m] = __builtin_amdgcn_exp2f(fmaf(w.x, xr, b1[m]) * NL2E);
    }
    if (threadIdx.x < 128) {
        const int g = threadIdx.x, m = g * 8;
        s16x8 h;
#pragma unroll
        for (int e = 0; e < 8; ++e) {
            const float2 w = reinterpret_cast<const float2*>(W1)[m + e];
            h[e] = (short)bf16_rn(__builtin_amdgcn_exp2f(w.y * xr * NL2E));
        }
        const int c = m >> 6;
        const int mg = g & 7;
        const int byte = (mg * 16) ^ ((r & 7) << 4);
        *reinterpret_cast<s16x8*>(&ECs[c * 49152 + r * 64 + (byte >> 1)]) = h;
    }
}

// ---- main-kernel macros (ambient locals) ---------------------------------------
#define STAGEW(cc, buf)                                                      \
    {                                                                        \
        const ushort* s_ = WhiS + (cc) * 8192;                               \
        _Pragma("unroll")                                                    \
        for (int q_ = 0; q_ < 4; ++q_) {                                     \
            const int o_ = (wv * 4 + q_) * 512;                              \
            GLOAD16(s_ + o_ + lane * 8, &Wh[buf][o_]);                       \
        }                                                                    \
    }

#define STAGEEC(cc, buf)                                                     \
    {                                                                        \
        const ushort* s_ = ECs + (cc) * 49152 + j0 * 64;                     \
        _Pragma("unroll")                                                    \
        for (int q_ = 0; q_ < 2; ++q_) {                                     \
            const int o_ = (wv * 2 + q_) * 512;                              \
            GLOAD16(s_ + o_ + lane * 8, &ECl[buf][o_]);                      \
        }                                                                    \
    }

// sigma = rcp(1 + EA*EC); 1 transcendental per value
#define SIGT(cc, buf)                                                        \
    {                                                                        \
        _Pragma("unroll")                                                    \
        for (int ks_ = 0; ks_ < 2; ++ks_) {                                  \
            const int m0_ = (cc) * 64 + ks_ * 32 + l4 * 8;                   \
            const f32x4 ea0_ = *reinterpret_cast<const f32x4*>(&EAl[m0_]);   \
            const f32x4 ea1_ = *reinterpret_cast<const f32x4*>(&EAl[m0_ + 4]); \
            const int jl_ = wv * 16 + l15;                                   \
            const int byte_ = (ks_ * 64 + l4 * 16) ^ ((jl_ & 7) << 4);       \
            union { s16x8 v; uint u[4]; } ec_;                               \
            ec_.v = *reinterpret_cast<const s16x8*>(&ECl[buf][jl_ * 64 + (byte_ >> 1)]); \
            union { s16x8 v; uint u[4]; } fr_;                               \
            _Pragma("unroll")                                                \
            for (int h_ = 0; h_ < 4; ++h_) {                                 \
                const uint uu_ = ec_.u[h_];                                  \
                const float el_ = __builtin_bit_cast(float, uu_ << 16);      \
                const float eh_ = __builtin_bit_cast(float, uu_ & 0xFFFF0000u); \
                const float ga_ = (h_ < 2) ? ea0_[2 * h_] : ea1_[2 * h_ - 4];     \
                const float gb_ = (h_ < 2) ? ea0_[2 * h_ + 1] : ea1_[2 * h_ - 3]; \
                const float t0_ = fmaf(el_, ga_, 1.0f);                      \
                const float t1_ = fmaf(eh_, gb_, 1.0f);                      \
                b16x2 p_;                                                    \
                p_.x = (__bf16)__builtin_amdgcn_rcpf(t0_);                   \
                p_.y = (__bf16)__builtin_amdgcn_rcpf(t1_);                   \
                fr_.u[h_] = __builtin_bit_cast(uint, p_);                    \
            }                                                                \
            ah[ks_] = fr_.v;                                                 \
        }                                                                    \
    }

#define MFMA8(buf)                                                           \
    {                                                                        \
        _Pragma("unroll")                                                    \
        for (int ks_ = 0; ks_ < 2; ++ks_) {                                  \
            s16x8 bh_[8];                                                    \
            _Pragma("unroll")                                                \
            for (int tn_ = 0; tn_ < 8; ++tn_) {                              \
                const int k_ = tn_ * 16 + l15;                               \
                const int byte_ = (ks_ * 64 + l4 * 16) ^ ((k_ & 7) << 4);    \
                bh_[tn_] = *reinterpret_cast<const s16x8*>(&Wh[buf][k_ * 64 + (byte_ >> 1)]); \
            }                                                                \
            __builtin_amdgcn_s_setprio(1);                                   \
            _Pragma("unroll")                                                \
            for (int tn_ = 0; tn_ < 8; ++tn_)                                \
                acc[tn_] = __builtin_amdgcn_mfma_f32_16x16x32_bf16(          \
                    ah[ks_], bh_[tn_], acc[tn_], 0, 0, 0);                   \
            __builtin_amdgcn_s_setprio(0);                                   \
        }                                                                    \
    }

// ---------- main: row-block (i, 64 j), 4 waves x (16 j x 128 k), tables --------
__global__ __launch_bounds__(256, 3) void mlp_rows(
    const float* __restrict__ EA, const ushort* __restrict__ ECs,
    const ushort* __restrict__ WhiS,
    const float* __restrict__ b2, const float* __restrict__ W3,
    const float* __restrict__ b3, float* __restrict__ K)
{
    const int i  = blockIdx.y;
    const int j0 = blockIdx.x * 64;
    if (j0 + 63 < i) return;                  // fully below diagonal

    __shared__ __align__(16) float EAl[MD];          // 4 KB
    __shared__ __align__(16) ushort ECl[2][4096];    // 16 KB
    __shared__ __align__(16) ushort Wh[2][8192];     // 32 KB

    const int t = threadIdx.x;
    const int lane = t & 63, wv = t >> 6;
    const int l15 = lane & 15, l4 = lane >> 4;

    // prologue: stage EA row + chunk 0 of EC and W2
    {
        const float* ea_ = EA + i * MD;
        const int o_ = wv * 256;
        GLOAD16(ea_ + o_ + lane * 4, &EAl[o_]);
    }
    STAGEEC(0, 0);
    STAGEW(0, 0);

    f32x4 acc[8];
#pragma unroll
    for (int b = 0; b < 8; ++b) acc[b] = (f32x4){0.f, 0.f, 0.f, 0.f};

    __syncthreads();                 // EA + chunk 0 resident (barrier drains vmcnt)

    s16x8 ah[2];
    for (int c = 0; c < 16; ++c) {
        if (c < 15) {
            STAGEEC(c + 1, (c + 1) & 1);     // async into other buffers
            STAGEW(c + 1, (c + 1) & 1);
        }
        SIGT(c, c & 1);                      // 1 rcp per sigmoid from tables
        MFMA8(c & 1);
        __syncthreads();             // next bufs ready; reads of cur bufs done
    }

    // epilogue: v = sum_k W3[k]*relu(h2 + b2[k]) + b3; reduce over 16 lanes (k)
    float w3v[8], b2v[8];
#pragma unroll
    for (int tn = 0; tn < 8; ++tn) {
        const int k = tn * 16 + l15;
        w3v[tn] = W3[k];
        b2v[tn] = b2[k];
    }
    const float b3v = b3[0];
#pragma unroll
    for (int r = 0; r < 4; ++r) {
        float v = 0.f;
#pragma unroll
        for (int tn = 0; tn < 8; ++tn)
            v = fmaf(w3v[tn], fmaxf(acc[tn][r] + b2v[tn], 0.f), v);
        v += __shfl_xor(v, 1, 16);
        v += __shfl_xor(v, 2, 16);
        v += __shfl_xor(v, 4, 16);
        v += __shfl_xor(v, 8, 16);
        if (l15 == 0) {
            const int j = j0 + wv * 16 + l4 * 4 + r;
            if (j >= i) K[i * NN + j] = v + b3v;
        }
    }
}

// ---------- fallback (R10 proven): pair-flattened, exp2-in-loop ----------------
#define FB_STAGE(cc)                                                         \
    {                                                                        \
        const ushort* sh_ = WhiS + (cc) * 8192;                              \
        ushort* ld_ = Whf[(cc) & 1];                                         \
        _Pragma("unroll")                                                    \
        for (int q_ = 0; q_ < 4; ++q_) {                                     \
            const int off_ = (wv * 4 + q_) * 512;                            \
            GLOAD16(sh_ + off_ + lane * 8, ld_ + off_);                      \
        }                                                                    \
    }

#define FB_SIG(cc, dst)                                                      \
    {                                                                        \
        _Pragma("unroll")                                                    \
        for (int ks_ = 0; ks_ < 2; ++ks_) {                                  \
            const int m0_ = (cc) * 64 + ks_ * 32 + l4 * 8;                   \
            const f32x4 a0_ = *reinterpret_cast<const f32x4*>(&sa[m0_]);     \
            const f32x4 a1_ = *reinterpret_cast<const f32x4*>(&sa[m0_ + 4]); \
            const f32x4 c0_ = *reinterpret_cast<const f32x4*>(&sc[m0_]);     \
            const f32x4 c1_ = *reinterpret_cast<const f32x4*>(&sc[m0_ + 4]); \
            const f32x4 b0_ = *reinterpret_cast<const f32x4*>(&sb[m0_]);     \
            const f32x4 b1_ = *reinterpret_cast<const f32x4*>(&sb[m0_ + 4]); \
            _Pragma("unroll")                                                \
            for (int tm_ = 0; tm_ < 2; ++tm_) {                              \
                float s_[8];                                                 \
                _Pragma("unroll")                                            \
                for (int e_ = 0; e_ < 4; ++e_) {                             \
                    const float u0_ = fmaf(xia[tm_], a0_[e_], fmaf(xja[tm_], c0_[e_], b0_[e_])); \
                    const float u1_ = fmaf(xia[tm_], a1_[e_], fmaf(xja[tm_], c1_[e_], b1_[e_])); \
                    s_[e_]     = __builtin_amdgcn_rcpf(1.0f + __builtin_amdgcn_exp2f(u0_)); \
                    s_[e_ + 4] = __builtin_amdgcn_rcpf(1.0f + __builtin_amdgcn_exp2f(u1_)); \
                }                                                            \
                union { s16x8 v; uint u[4]; } fr_;                           \
                _Pragma("unroll")                                            \
                for (int h_ = 0; h_ < 4; ++h_) {                             \
                    b16x2 p_;                                                \
                    p_.x = (__bf16)s_[2 * h_];                               \
                    p_.y = (__bf16)s_[2 * h_ + 1];                           \
                    fr_.u[h_] = __builtin_bit_cast(uint, p_);                \
                }                                                            \
                dst[ks_][tm_] = fr_.v;                                       \
            }                                                                \
        }                                                                    \
    }

#define FB_MFMA(cc, src)                                                     \
    {                                                                        \
        const ushort* wb_ = Whf[(cc) & 1];                                   \
        _Pragma("unroll")                                                    \
        for (int ks_ = 0; ks_ < 2; ++ks_) {                                  \
            _Pragma("unroll")                                                \
            for (int th_ = 0; th_ < 2; ++th_) {                              \
                s16x8 bh_[4];                                                \
                _Pragma("unroll")                                            \
                for (int tn_ = 0; tn_ < 4; ++tn_) {                          \
                    const int k_ = th_ * 64 + tn_ * 16 + l15;                \
                    const int byte_ = (ks_ * 64 + l4 * 16) ^ ((k_ & 7) << 4);\
                    const int idx_ = (k_ * 128 + byte_) >> 1;                \
                    bh_[tn_] = *reinterpret_cast<const s16x8*>(&wb_[idx_]);  \
                }                                                            \
                __builtin_amdgcn_s_setprio(1);                               \
                _Pragma("unroll")                                            \
                for (int tm_ = 0; tm_ < 2; ++tm_)                            \
                    _Pragma("unroll")                                        \
                    for (int tn_ = 0; tn_ < 4; ++tn_)                        \
                        accf[tm_][th_][tn_] = __builtin_amdgcn_mfma_f32_16x16x32_bf16( \
                            src[ks_][tm_], bh_[tn_], accf[tm_][th_][tn_], 0, 0, 0);    \
                __builtin_amdgcn_s_setprio(0);                               \
            }                                                                \
        }                                                                    \
    }

__global__ __launch_bounds__(256, 3) void mlp_pairs(
    const float* __restrict__ x,
    const float* __restrict__ W1, const float* __restrict__ b1,
    const ushort* __restrict__ WhiS,
    const float* __restrict__ b2, const float* __restrict__ W3,
    const float* __restrict__ b3, float* __restrict__ K)
{
    __shared__ __align__(16) float sa[MD], sc[MD], sb[MD];
    __shared__ __align__(16) ushort Whf[2][8192];

    const int t = threadIdx.x;
    const int lane = t & 63, wv = t >> 6;
    const int l15 = lane & 15, l4 = lane >> 4;

    const float NL2E = -1.4426950408889634f;
    for (int m = t; m < MD; m += 256) {
        const float2 w = reinterpret_cast<const float2*>(W1)[m];
        sa[m] = w.x * NL2E;
        sc[m] = w.y * NL2E;
        sb[m] = b1[m] * NL2E;
    }

    const int pairbase = blockIdx.x * 128 + wv * 32;

    float xia[2], xja[2];
#pragma unroll
    for (int tm = 0; tm < 2; ++tm) {
        const int p = pairbase + tm * 16 + l15;
        if (p < NPAIR) {
            int i, j;
            ptoij(p, i, j);
            xia[tm] = x[i];
            xja[tm] = x[j];
        } else {
            xia[tm] = 0.f;
            xja[tm] = 0.f;
        }
    }

    f32x4 accf[2][2][4];
#pragma unroll
    for (int a = 0; a < 2; ++a)
#pragma unroll
        for (int th = 0; th < 2; ++th)
#pragma unroll
            for (int b = 0; b < 4; ++b) accf[a][th][b] = (f32x4){0.f, 0.f, 0.f, 0.f};

    FB_STAGE(0);
    __syncthreads();

    s16x8 ah[2][2];
    for (int c = 0; c < 16; ++c) {
        if (c < 15) FB_STAGE(c + 1);
        FB_SIG(c, ah);
        FB_MFMA(c, ah);
        __syncthreads();
    }

    float w3v[2][4], b2v[2][4];
#pragma unroll
    for (int th = 0; th < 2; ++th)
#pragma unroll
        for (int tn = 0; tn < 4; ++tn) {
            const int k = th * 64 + tn * 16 + l15;
            w3v[th][tn] = W3[k];
            b2v[th][tn] = b2[k];
        }
    const float b3v = b3[0];
#pragma unroll
    for (int tm = 0; tm < 2; ++tm)
#pragma unroll
        for (int r = 0; r < 4; ++r) {
            float v = 0.f;
#pragma unroll
            for (int th = 0; th < 2; ++th)
#pragma unroll
                for (int tn = 0; tn < 4; ++tn)
                    v = fmaf(w3v[th][tn], fmaxf(accf[tm][th][tn][r] + b2v[th][tn], 0.f), v);
            v += __shfl_xor(v, 1, 16);
            v += __shfl_xor(v, 2, 16);
            v += __shfl_xor(v, 4, 16);
            v += __shfl_xor(v, 8, 16);
            if (l15 == 0) {
                const int p = pairbase + tm * 16 + l4 * 4 + r;
                if (p < NPAIR) {
                    int i, j;
                    ptoij(p, i, j);
                    K[i * NN + j] = v + b3v;
                }
            }
        }
}

// ---------------- Kernel 2: C = K^T K (768^3 fp32 GEMM) --------------------
__global__ __launch_bounds__(256) void ktk(const float* __restrict__ K,
                                           float* __restrict__ C)
{
    const int b0 = blockIdx.x * 64;
    const int a0 = blockIdx.y * 64;
    __shared__ float Ka[64][68];
    __shared__ float Kb[64][68];
    const int t  = threadIdx.x;
    const int tb = t & 15;
    const int ta = t >> 4;
    float acc[4][4];
#pragma unroll
    for (int u = 0; u < 4; u++)
#pragma unroll
        for (int v = 0; v < 4; v++) acc[u][v] = 0.f;
    const int kmax = (a0 < b0 ? a0 : b0) + 64;
    for (int k0 = 0; k0 < kmax; k0 += 64) {
#pragma unroll
        for (int q = 0; q < 4; q++) {
            const int f  = t + q * 256;
            const int kk = f >> 4;
            const int c4 = (f & 15) * 4;
            *reinterpret_cast<float4*>(&Ka[kk][c4]) =
                *reinterpret_cast<const float4*>(K + (k0 + kk) * NN + a0 + c4);
            *reinterpret_cast<float4*>(&Kb[kk][c4]) =
                *reinterpret_cast<const float4*>(K + (k0 + kk) * NN + b0 + c4);
        }
        __syncthreads();
#pragma unroll 8
        for (int kk = 0; kk < 64; kk++) {
            const float4 av = *reinterpret_cast<const float4*>(&Ka[kk][ta * 4]);
            const float4 bv = *reinterpret_cast<const float4*>(&Kb[kk][tb * 4]);
            const float a4[4] = {av.x, av.y, av.z, av.w};
            const float b4[4] = {bv.x, bv.y, bv.z, bv.w};
#pragma unroll
            for (int u = 0; u < 4; u++)
#pragma unroll
                for (int v = 0; v < 4; v++)
                    acc[u][v] = fmaf(a4[u], b4[v], acc[u][v]);
        }
        __syncthreads();
    }
#pragma unroll
    for (int u = 0; u < 4; u++) {
        float4 o;
        o.x = acc[u][0]; o.y = acc[u][1]; o.z = acc[u][2]; o.w = acc[u][3];
        *reinterpret_cast<float4*>(C + (a0 + ta * 4 + u) * NN + b0 + tb * 4) = o;
    }
}

extern "C" void kernel_launch(void* const* d_in, const int* in_sizes, int n_in,
                              void* d_out, int out_size, void* d_ws, size_t ws_size,
                              hipStream_t stream)
{
    const float* x  = (const float*)d_in[0];
    const float* W1 = (const float*)d_in[1];
    const float* b1 = (const float*)d_in[2];
    const float* W2 = (const float*)d_in[3];
    const float* b2 = (const float*)d_in[4];
    const float* W3 = (const float*)d_in[5];
    const float* b3 = (const float*)d_in[6];
    float* Kmat = (float*)d_ws;                       // 2,359,296 B
    float* C    = (float*)d_out;

    const size_t kBytes = (size_t)NN * NN * sizeof(float);
    const size_t wBytes = 262144;                     // W2 bf16 swizzled
    const size_t eaB    = (size_t)NN * MD * sizeof(float);     // 3 MB
    const size_t ecB    = (size_t)16 * 49152 * sizeof(ushort); // 1.5 MB
    const size_t needNew = kBytes + wBytes + eaB + ecB;        // ~7.34 MB
    const size_t needFB  = kBytes + wBytes;                    // ~2.6 MB

    hipMemsetAsync(Kmat, 0, kBytes, stream);
    if (ws_size >= needNew) {
        ushort* WhiS = (ushort*)((char*)d_ws + kBytes);
        float*  EA   = (float*)((char*)d_ws + kBytes + wBytes);
        ushort* ECs  = (ushort*)((char*)d_ws + kBytes + wBytes + eaB);
        w2bf16<<<64, 256, 0, stream>>>(W2, WhiS);
        etab2<<<NN, 256, 0, stream>>>(x, W1, b1, EA, ECs);
        mlp_rows<<<dim3(12, NN), 256, 0, stream>>>(EA, ECs, WhiS, b2, W3, b3, Kmat);
    } else if (ws_size >= needFB) {
        ushort* WhiS = (ushort*)((char*)d_ws + kBytes);
        w2bf16<<<64, 256, 0, stream>>>(W2, WhiS);
        mlp_pairs<<<NPBLK2, 256, 0, stream>>>(x, W1, b1, WhiS, b2, W3, b3, Kmat);
    }
    ktk<<<dim3(NN / 64, NN / 64), 256, 0, stream>>>(Kmat, C);
}

// Round 13
// 174.436 us; speedup vs baseline: 1.1095x; 1.1095x over previous
//
#include <hip/hip_runtime.h>
#include <hip/hip_bf16.h>

#define NN 768
#define MD 1024
#define NPAIR 295296            // 768*769/2
#define NPBLK2 2307             // NPAIR / 128 (exact)

typedef __attribute__((ext_vector_type(8))) short s16x8;
typedef __attribute__((ext_vector_type(4))) float f32x4;
typedef __attribute__((ext_vector_type(2))) float f32x2;
typedef __attribute__((ext_vector_type(2))) __bf16 b16x2;

__device__ __forceinline__ ushort bf16_rn(float f) {
    uint u = __builtin_bit_cast(uint, f);
    u += 0x7FFFu + ((u >> 16) & 1u);
    return (ushort)(u >> 16);
}

// inverse triangular index: p -> (i,j), off(i) = i*(1537-i)/2, j = i + p - off(i)
__device__ __forceinline__ void ptoij(int p, int& io, int& jo) {
    const float disc = (float)(1537 * 1537 - 8 * p);
    int i = (int)((1537.0f - sqrtf(disc)) * 0.5f);
    i = i < 0 ? 0 : (i > 767 ? 767 : i);
    while (i > 0 && p < i * (1537 - i) / 2) --i;
    while (i < 767 && p >= (i + 1) * (1536 - i) / 2) ++i;
    io = i;
    jo = i + (p - i * (1537 - i) / 2);
}

#define GLOAD16(gsrc, ldst)                                                        \
    __builtin_amdgcn_global_load_lds(                                              \
        (const __attribute__((address_space(1))) void*)(gsrc),                     \
        (__attribute__((address_space(3))) void*)(ldst), 16, 0, 0)

// ---------- one-time: W2 -> bf16 (RNE), chunk-major + XOR-swizzled -------------
// chunk c (m0=c*64): 128 rows(k) x 128B; byte-in-row = (mloc8*16) ^ ((k&7)<<4)
__global__ __launch_bounds__(256) void w2bf16(const float* __restrict__ W2,
                                              ushort* __restrict__ WhiS)
{
    const int id = blockIdx.x * 256 + threadIdx.x;
    const int k = id >> 7;
    const int m = (id & 127) * 8;
    const float4 a = *reinterpret_cast<const float4*>(W2 + k * MD + m);
    const float4 b = *reinterpret_cast<const float4*>(W2 + k * MD + m + 4);
    const float w[8] = {a.x, a.y, a.z, a.w, b.x, b.y, b.z, b.w};
    s16x8 h;
#pragma unroll
    for (int e = 0; e < 8; ++e) h[e] = (short)bf16_rn(w[e]);
    const int c = m >> 6;
    const int mloc8 = (m >> 3) & 7;
    const int byte = (mloc8 * 16) ^ ((k & 7) << 4);
    const int off = c * 8192 + ((k * 128 + byte) >> 1);
    *reinterpret_cast<s16x8*>(&WhiS[off]) = h;
}

// ---- macros (ambient locals) ---------------------------------------------------
#define STAGE(cc)                                                            \
    {                                                                        \
        const ushort* sh_ = WhiS + (cc) * 8192;                              \
        ushort* ld_ = Wh[(cc) & 1];                                          \
        _Pragma("unroll")                                                    \
        for (int q_ = 0; q_ < 4; ++q_) {                                     \
            const int off_ = (wv * 4 + q_) * 512;                            \
            GLOAD16(sh_ + off_ + lane * 8, ld_ + off_);                      \
        }                                                                    \
    }

// weights in sa/sc/sb pre-scaled by -log2(e): sigma = rcp(1 + 2^u)
#define SIG_CHUNK(cc, dst)                                                   \
    {                                                                        \
        _Pragma("unroll")                                                    \
        for (int ks_ = 0; ks_ < 2; ++ks_) {                                  \
            const int m0_ = (cc) * 64 + ks_ * 32 + l4 * 8;                   \
            const f32x4 a0_ = *reinterpret_cast<const f32x4*>(&sa[m0_]);     \
            const f32x4 a1_ = *reinterpret_cast<const f32x4*>(&sa[m0_ + 4]); \
            const f32x4 c0_ = *reinterpret_cast<const f32x4*>(&sc[m0_]);     \
            const f32x4 c1_ = *reinterpret_cast<const f32x4*>(&sc[m0_ + 4]); \
            const f32x4 b0_ = *reinterpret_cast<const f32x4*>(&sb[m0_]);     \
            const f32x4 b1_ = *reinterpret_cast<const f32x4*>(&sb[m0_ + 4]); \
            _Pragma("unroll")                                                \
            for (int tm_ = 0; tm_ < 2; ++tm_) {                              \
                const f32x2 xi2_ = (f32x2){xia[tm_], xia[tm_]};              \
                const f32x2 xj2_ = (f32x2){xja[tm_], xja[tm_]};              \
                const f32x2 one2_ = (f32x2){1.f, 1.f};                       \
                union { s16x8 v; uint u[4]; } fr_;                           \
                _Pragma("unroll")                                            \
                for (int h_ = 0; h_ < 4; ++h_) {                             \
                    f32x2 av_, cv_, bv_;                                     \
                    if (h_ < 2) {                                            \
                        av_ = (f32x2){a0_[2 * h_], a0_[2 * h_ + 1]};         \
                        cv_ = (f32x2){c0_[2 * h_], c0_[2 * h_ + 1]};         \
                        bv_ = (f32x2){b0_[2 * h_], b0_[2 * h_ + 1]};         \
                    } else {                                                 \
                        av_ = (f32x2){a1_[2 * h_ - 4], a1_[2 * h_ - 3]};     \
                        cv_ = (f32x2){c1_[2 * h_ - 4], c1_[2 * h_ - 3]};     \
                        bv_ = (f32x2){b1_[2 * h_ - 4], b1_[2 * h_ - 3]};     \
                    }                                                        \
                    const f32x2 u2_ = __builtin_elementwise_fma(             \
                        xi2_, av_, __builtin_elementwise_fma(xj2_, cv_, bv_));\
                    f32x2 e2_;                                               \
                    e2_[0] = __builtin_amdgcn_exp2f(u2_[0]);                 \
                    e2_[1] = __builtin_amdgcn_exp2f(u2_[1]);                 \
                    const f32x2 t2_ = e2_ + one2_;                           \
                    b16x2 p_;                                                \
                    p_.x = (__bf16)__builtin_amdgcn_rcpf(t2_[0]);            \
                    p_.y = (__bf16)__builtin_amdgcn_rcpf(t2_[1]);            \
                    fr_.u[h_] = __builtin_bit_cast(uint, p_);                \
                }                                                            \
                dst[ks_][tm_] = fr_.v;                                       \
            }                                                                \
        }                                                                    \
    }

#define MFMA_STEP(cc, src)                                                   \
    {                                                                        \
        const ushort* wb_ = Wh[(cc) & 1];                                    \
        _Pragma("unroll")                                                    \
        for (int ks_ = 0; ks_ < 2; ++ks_) {                                  \
            _Pragma("unroll")                                                \
            for (int th_ = 0; th_ < 2; ++th_) {                              \
                s16x8 bh_[4];                                                \
                _Pragma("unroll")                                            \
                for (int tn_ = 0; tn_ < 4; ++tn_) {                          \
                    const int k_ = th_ * 64 + tn_ * 16 + l15;                \
                    const int byte_ = (ks_ * 64 + l4 * 16) ^ ((k_ & 7) << 4);\
                    const int idx_ = (k_ * 128 + byte_) >> 1;                \
                    bh_[tn_] = *reinterpret_cast<const s16x8*>(&wb_[idx_]);  \
                }                                                            \
                __builtin_amdgcn_s_setprio(1);                               \
                _Pragma("unroll")                                            \
                for (int tm_ = 0; tm_ < 2; ++tm_)                            \
                    _Pragma("unroll")                                        \
                    for (int tn_ = 0; tn_ < 4; ++tn_)                        \
                        acc[tm_][th_][tn_] = __builtin_amdgcn_mfma_f32_16x16x32_bf16( \
                            src[ks_][tm_], bh_[tn_], acc[tm_][th_][tn_], 0, 0, 0);    \
                __builtin_amdgcn_s_setprio(0);                               \
            }                                                                \
        }                                                                    \
    }

// ---------- main (R8-proven): 32 pairs/wave, 3 waves/SIMD ----------------------
__global__ __launch_bounds__(256, 3) void mlp_pairs(
    const float* __restrict__ x,
    const float* __restrict__ W1, const float* __restrict__ b1,
    const ushort* __restrict__ WhiS,
    const float* __restrict__ b2, const float* __restrict__ W3,
    const float* __restrict__ b3, float* __restrict__ K)
{
    __shared__ __align__(16) float sa[MD], sc[MD], sb[MD];
    __shared__ __align__(16) ushort Wh[2][8192];

    const int t = threadIdx.x;
    const int lane = t & 63, wv = t >> 6;
    const int l15 = lane & 15, l4 = lane >> 4;

    const float NL2E = -1.4426950408889634f;
    for (int m = t; m < MD; m += 256) {
        const float2 w = reinterpret_cast<const float2*>(W1)[m];
        sa[m] = w.x * NL2E;
        sc[m] = w.y * NL2E;
        sb[m] = b1[m] * NL2E;
    }

    const int pairbase = blockIdx.x * 128 + wv * 32;

    float xia[2], xja[2];
#pragma unroll
    for (int tm = 0; tm < 2; ++tm) {
        const int p = pairbase + tm * 16 + l15;
        if (p < NPAIR) {
            int i, j;
            ptoij(p, i, j);
            xia[tm] = x[i];
            xja[tm] = x[j];
        } else {
            xia[tm] = 0.f;
            xja[tm] = 0.f;
        }
    }

    f32x4 acc[2][2][4];
#pragma unroll
    for (int a = 0; a < 2; ++a)
#pragma unroll
        for (int th = 0; th < 2; ++th)
#pragma unroll
            for (int b = 0; b < 4; ++b) acc[a][th][b] = (f32x4){0.f, 0.f, 0.f, 0.f};

    STAGE(0);
    __syncthreads();                 // sa/sc/sb written AND Wh[0] staged

    s16x8 ah[2][2];
    for (int c = 0; c < 16; ++c) {
        if (c < 15) STAGE(c + 1);    // async into other buffer
        SIG_CHUNK(c, ah);            // VALU while loads fly
        MFMA_STEP(c, ah);
        __syncthreads();             // next buf ready; all reads of cur buf done
    }

    // epilogue: v = sum_k W3[k]*relu(h2 + b2[k]) + b3; reduce over 16 lanes (k)
    float w3v[2][4], b2v[2][4];
#pragma unroll
    for (int th = 0; th < 2; ++th)
#pragma unroll
        for (int tn = 0; tn < 4; ++tn) {
            const int k = th * 64 + tn * 16 + l15;
            w3v[th][tn] = W3[k];
            b2v[th][tn] = b2[k];
        }
    const float b3v = b3[0];
#pragma unroll
    for (int tm = 0; tm < 2; ++tm)
#pragma unroll
        for (int r = 0; r < 4; ++r) {
            float v = 0.f;
#pragma unroll
            for (int th = 0; th < 2; ++th)
#pragma unroll
                for (int tn = 0; tn < 4; ++tn)
                    v = fmaf(w3v[th][tn], fmaxf(acc[tm][th][tn][r] + b2v[th][tn], 0.f), v);
            v += __shfl_xor(v, 1, 16);
            v += __shfl_xor(v, 2, 16);
            v += __shfl_xor(v, 4, 16);
            v += __shfl_xor(v, 8, 16);
            if (l15 == 0) {
                const int p = pairbase + tm * 16 + l4 * 4 + r;
                if (p < NPAIR) {
                    int i, j;
                    ptoij(p, i, j);
                    K[i * NN + j] = v + b3v;
                }
            }
        }
}

// ---------- fallback fp32 MLP kernel (only if ws too small; never expected) ----
#define MC 32
#define JT 128
#define SPAD 132
__global__ __launch_bounds__(256) void mlp_fill(
    const float* __restrict__ x,
    const float* __restrict__ W1, const float* __restrict__ b1,
    const float* __restrict__ W2, const float* __restrict__ b2,
    const float* __restrict__ W3, const float* __restrict__ b3,
    float* __restrict__ K)
{
    const int i  = blockIdx.y;
    const int j0 = blockIdx.x * JT;
    if (j0 + JT - 1 < i) return;
    __shared__ float sA[MD];
    __shared__ float sCw[MD];
    __shared__ float sxj[JT];
    __shared__ float S[MC][SPAD];
    __shared__ float W2t[MC][SPAD];
    const int t = threadIdx.x;
    const float xi = x[i];
    for (int m = t; m < MD; m += 256) {
        const float2 w = reinterpret_cast<const float2*>(W1)[m];
        sA[m]  = fmaf(xi, w.x, b1[m]);
        sCw[m] = w.y;
    }
    if (t < JT) sxj[t] = x[j0 + t];
    const int tk = t & 15;
    const int tj = t >> 4;
    float w3r[8], b2r[8];
#pragma unroll
    for (int kk = 0; kk < 8; kk++) {
        w3r[kk] = W3[tk * 8 + kk];
        b2r[kk] = b2[tk * 8 + kk];
    }
    float acc[8][8];
#pragma unroll
    for (int jj = 0; jj < 8; jj++)
#pragma unroll
        for (int kk = 0; kk < 8; kk++) acc[jj][kk] = 0.f;
    const int jx   = t & 127;
    const int mseg = (t >> 7) * 16;
    __syncthreads();
    const float xjv = sxj[jx];
    for (int m0 = 0; m0 < MD; m0 += MC) {
#pragma unroll
        for (int q = 0; q < 4; q++) {
            const int f   = t + q * 256;
            const int k   = f >> 3;
            const int mm4 = (f & 7) * 4;
            const float4 w = *reinterpret_cast<const float4*>(W2 + k * MD + m0 + mm4);
            W2t[mm4 + 0][k] = w.x;
            W2t[mm4 + 1][k] = w.y;
            W2t[mm4 + 2][k] = w.z;
            W2t[mm4 + 3][k] = w.w;
        }
#pragma unroll
        for (int q = 0; q < 16; q++) {
            const int ml = mseg + q;
            const float z = fmaf(xjv, sCw[m0 + ml], sA[m0 + ml]);
            S[ml][jx] = 1.0f / (1.0f + __expf(-z));
        }
        __syncthreads();
#pragma unroll 4
        for (int mm = 0; mm < MC; mm++) {
            const float4 s0 = *reinterpret_cast<const float4*>(&S[mm][tj * 8]);
            const float4 s1 = *reinterpret_cast<const float4*>(&S[mm][tj * 8 + 4]);
            const float4 w0 = *reinterpret_cast<const float4*>(&W2t[mm][tk * 8]);
            const float4 w1 = *reinterpret_cast<const float4*>(&W2t[mm][tk * 8 + 4]);
            const float sj[8] = {s0.x, s0.y, s0.z, s0.w, s1.x, s1.y, s1.z, s1.w};
            const float wk[8] = {w0.x, w0.y, w0.z, w0.w, w1.x, w1.y, w1.z, w1.w};
#pragma unroll
            for (int jj = 0; jj < 8; jj++)
#pragma unroll
                for (int kk = 0; kk < 8; kk++)
                    acc[jj][kk] = fmaf(sj[jj], wk[kk], acc[jj][kk]);
        }
        __syncthreads();
    }
    const float b3v = b3[0];
#pragma unroll
    for (int jj = 0; jj < 8; jj++) {
        float v = 0.f;
#pragma unroll
        for (int kk = 0; kk < 8; kk++) {
            const float h = acc[jj][kk] + b2r[kk];
            v = fmaf(w3r[kk], fmaxf(h, 0.f), v);
        }
#pragma unroll
        for (int off = 8; off >= 1; off >>= 1)
            v += __shfl_xor(v, off, 16);
        if (tk == 0) {
            const int j = j0 + tj * 8 + jj;
            if (j >= i) K[i * NN + j] = v + b3v;
        }
    }
}

// ---------- Kernel 2: C = K^T K, symmetric — compute upper tiles, mirror -------
__global__ __launch_bounds__(256) void ktk(const float* __restrict__ K,
                                           float* __restrict__ C)
{
    const int b0 = blockIdx.x * 64;
    const int a0 = blockIdx.y * 64;
    if (b0 < a0) return;             // C symmetric: only tiles with b0 >= a0
    __shared__ float Ka[64][68];
    __shared__ float Kb[64][68];
    const int t  = threadIdx.x;
    const int tb = t & 15;
    const int ta = t >> 4;
    float acc[4][4];
#pragma unroll
    for (int u = 0; u < 4; u++)
#pragma unroll
        for (int v = 0; v < 4; v++) acc[u][v] = 0.f;
    const int kmax = a0 + 64;        // K[k][a]=0 for k>a; a0 <= b0
    for (int k0 = 0; k0 < kmax; k0 += 64) {
#pragma unroll
        for (int q = 0; q < 4; q++) {
            const int f  = t + q * 256;
            const int kk = f >> 4;
            const int c4 = (f & 15) * 4;
            *reinterpret_cast<float4*>(&Ka[kk][c4]) =
                *reinterpret_cast<const float4*>(K + (k0 + kk) * NN + a0 + c4);
            *reinterpret_cast<float4*>(&Kb[kk][c4]) =
                *reinterpret_cast<const float4*>(K + (k0 + kk) * NN + b0 + c4);
        }
        __syncthreads();
#pragma unroll 8
        for (int kk = 0; kk < 64; kk++) {
            const float4 av = *reinterpret_cast<const float4*>(&Ka[kk][ta * 4]);
            const float4 bv = *reinterpret_cast<const float4*>(&Kb[kk][tb * 4]);
            const float a4[4] = {av.x, av.y, av.z, av.w};
            const float b4[4] = {bv.x, bv.y, bv.z, bv.w};
#pragma unroll
            for (int u = 0; u < 4; u++)
#pragma unroll
                for (int v = 0; v < 4; v++)
                    acc[u][v] = fmaf(a4[u], b4[v], acc[u][v]);
        }
        __syncthreads();
    }
#pragma unroll
    for (int u = 0; u < 4; u++) {
        float4 o;
        o.x = acc[u][0]; o.y = acc[u][1]; o.z = acc[u][2]; o.w = acc[u][3];
        *reinterpret_cast<float4*>(C + (a0 + ta * 4 + u) * NN + b0 + tb * 4) = o;
    }
    if (b0 > a0) {                   // mirror tile: C[b][a] = C[a][b], coalesced
#pragma unroll
        for (int v = 0; v < 4; v++) {
            float4 o;
            o.x = acc[0][v]; o.y = acc[1][v]; o.z = acc[2][v]; o.w = acc[3][v];
            *reinterpret_cast<float4*>(C + (b0 + tb * 4 + v) * NN + a0 + ta * 4) = o;
        }
    }
}

extern "C" void kernel_launch(void* const* d_in, const int* in_sizes, int n_in,
                              void* d_out, int out_size, void* d_ws, size_t ws_size,
                              hipStream_t stream)
{
    const float* x  = (const float*)d_in[0];
    const float* W1 = (const float*)d_in[1];
    const float* b1 = (const float*)d_in[2];
    const float* W2 = (const float*)d_in[3];
    const float* b2 = (const float*)d_in[4];
    const float* W3 = (const float*)d_in[5];
    const float* b3 = (const float*)d_in[6];
    float* Kmat = (float*)d_ws;                       // 2,359,296 B
    float* C    = (float*)d_out;

    const size_t kBytes = (size_t)NN * NN * sizeof(float);
    const size_t need   = kBytes + 262144;            // + W2 bf16 swizzled

    hipMemsetAsync(Kmat, 0, kBytes, stream);
    if (ws_size >= need) {
        ushort* WhiS = (ushort*)((char*)d_ws + kBytes);
        w2bf16<<<64, 256, 0, stream>>>(W2, WhiS);
        mlp_pairs<<<NPBLK2, 256, 0, stream>>>(x, W1, b1, WhiS, b2, W3, b3, Kmat);
    } else {
        mlp_fill<<<dim3(6, NN), 256, 0, stream>>>(x, W1, b1, W2, b2, W3, b3, Kmat);
    }
    ktk<<<dim3(NN / 64, NN / 64), 256, 0, stream>>>(Kmat, C);
}

// Round 14
// 169.013 us; speedup vs baseline: 1.1451x; 1.0321x over previous
//
#include <hip/hip_runtime.h>
#include <hip/hip_bf16.h>

#define NN 768
#define MD 1024
#define NPAIR 295296            // 768*769/2
#define NPBLK2 2307             // NPAIR / 128 (exact)

typedef __attribute__((ext_vector_type(8))) short s16x8;
typedef __attribute__((ext_vector_type(4))) float f32x4;
typedef __attribute__((ext_vector_type(2))) float f32x2;
typedef __attribute__((ext_vector_type(2))) __bf16 b16x2;

__device__ __forceinline__ ushort bf16_rn(float f) {
    uint u = __builtin_bit_cast(uint, f);
    u += 0x7FFFu + ((u >> 16) & 1u);
    return (ushort)(u >> 16);
}

// inverse triangular index: p -> (i,j), off(i) = i*(1537-i)/2, j = i + p - off(i)
__device__ __forceinline__ void ptoij(int p, int& io, int& jo) {
    const float disc = (float)(1537 * 1537 - 8 * p);
    int i = (int)((1537.0f - sqrtf(disc)) * 0.5f);
    i = i < 0 ? 0 : (i > 767 ? 767 : i);
    while (i > 0 && p < i * (1537 - i) / 2) --i;
    while (i < 767 && p >= (i + 1) * (1536 - i) / 2) ++i;
    io = i;
    jo = i + (p - i * (1537 - i) / 2);
}

// ---------- one-time: W2 -> bf16, FRAGMENT-major for register-direct loads -----
// frag f = ((c*2+ks)*8 + tn); WF[f*512 + lane*8 + e] = W2bf16[k][m]
// with k = tn*16 + (lane&15), m = c*64 + ks*32 + (lane>>4)*8 + e
__global__ __launch_bounds__(256) void w2frag(const float* __restrict__ W2,
                                              ushort* __restrict__ WF)
{
    const int id = blockIdx.x * 256 + threadIdx.x;   // 0..16383
    const int lane = id & 63;
    const int f = id >> 6;          // 0..255
    const int tn = f & 7;
    const int ks = (f >> 3) & 1;
    const int c  = f >> 4;
    const int k = tn * 16 + (lane & 15);
    const int m = c * 64 + ks * 32 + (lane >> 4) * 8;
    const float4 a = *reinterpret_cast<const float4*>(W2 + k * MD + m);
    const float4 b = *reinterpret_cast<const float4*>(W2 + k * MD + m + 4);
    const float w[8] = {a.x, a.y, a.z, a.w, b.x, b.y, b.z, b.w};
    s16x8 h;
#pragma unroll
    for (int e = 0; e < 8; ++e) h[e] = (short)bf16_rn(w[e]);
    *reinterpret_cast<s16x8*>(WF + id * 8) = h;
}

// ---- macros (ambient locals) ---------------------------------------------------
// load one ks-half of a chunk's B-fragments into registers (8 coalesced 1KB loads)
#define LOADB(cc, ks)                                                        \
    {                                                                        \
        const ushort* wb_ = WF + (cc) * 8192 + (ks) * 4096 + lane * 8;       \
        _Pragma("unroll")                                                    \
        for (int tn_ = 0; tn_ < 8; ++tn_)                                    \
            bh[tn_] = *reinterpret_cast<const s16x8*>(wb_ + tn_ * 512);      \
    }

// weights in sa/sc/sb pre-scaled by -log2(e): sigma = rcp(1 + 2^u)
#define SIG_CHUNK(cc, dst)                                                   \
    {                                                                        \
        _Pragma("unroll")                                                    \
        for (int ks_ = 0; ks_ < 2; ++ks_) {                                  \
            const int m0_ = (cc) * 64 + ks_ * 32 + l4 * 8;                   \
            const f32x4 a0_ = *reinterpret_cast<const f32x4*>(&sa[m0_]);     \
            const f32x4 a1_ = *reinterpret_cast<const f32x4*>(&sa[m0_ + 4]); \
            const f32x4 c0_ = *reinterpret_cast<const f32x4*>(&sc[m0_]);     \
            const f32x4 c1_ = *reinterpret_cast<const f32x4*>(&sc[m0_ + 4]); \
            const f32x4 b0_ = *reinterpret_cast<const f32x4*>(&sb[m0_]);     \
            const f32x4 b1_ = *reinterpret_cast<const f32x4*>(&sb[m0_ + 4]); \
            _Pragma("unroll")                                                \
            for (int tm_ = 0; tm_ < 2; ++tm_) {                              \
                const f32x2 xi2_ = (f32x2){xia[tm_], xia[tm_]};              \
                const f32x2 xj2_ = (f32x2){xja[tm_], xja[tm_]};              \
                const f32x2 one2_ = (f32x2){1.f, 1.f};                       \
                union { s16x8 v; uint u[4]; } fr_;                           \
                _Pragma("unroll")                                            \
                for (int h_ = 0; h_ < 4; ++h_) {                             \
                    f32x2 av_, cv_, bv_;                                     \
                    if (h_ < 2) {                                            \
                        av_ = (f32x2){a0_[2 * h_], a0_[2 * h_ + 1]};         \
                        cv_ = (f32x2){c0_[2 * h_], c0_[2 * h_ + 1]};         \
                        bv_ = (f32x2){b0_[2 * h_], b0_[2 * h_ + 1]};         \
                    } else {                                                 \
                        av_ = (f32x2){a1_[2 * h_ - 4], a1_[2 * h_ - 3]};     \
                        cv_ = (f32x2){c1_[2 * h_ - 4], c1_[2 * h_ - 3]};     \
                        bv_ = (f32x2){b1_[2 * h_ - 4], b1_[2 * h_ - 3]};     \
                    }                                                        \
                    const f32x2 u2_ = __builtin_elementwise_fma(             \
                        xi2_, av_, __builtin_elementwise_fma(xj2_, cv_, bv_));\
                    f32x2 e2_;                                               \
                    e2_[0] = __builtin_amdgcn_exp2f(u2_[0]);                 \
                    e2_[1] = __builtin_amdgcn_exp2f(u2_[1]);                 \
                    const f32x2 t2_ = e2_ + one2_;                           \
                    b16x2 p_;                                                \
                    p_.x = (__bf16)__builtin_amdgcn_rcpf(t2_[0]);            \
                    p_.y = (__bf16)__builtin_amdgcn_rcpf(t2_[1]);            \
                    fr_.u[h_] = __builtin_bit_cast(uint, p_);                \
                }                                                            \
                dst[ks_][tm_] = fr_.v;                                       \
            }                                                                \
        }                                                                    \
    }

#define MFMA_HALF(ks)                                                        \
    {                                                                        \
        __builtin_amdgcn_s_setprio(1);                                       \
        _Pragma("unroll")                                                    \
        for (int tm_ = 0; tm_ < 2; ++tm_)                                    \
            _Pragma("unroll")                                                \
            for (int tn_ = 0; tn_ < 8; ++tn_)                                \
                acc[tm_][tn_] = __builtin_amdgcn_mfma_f32_16x16x32_bf16(     \
                    ah[ks][tm_], bh[tn_], acc[tm_][tn_], 0, 0, 0);           \
        __builtin_amdgcn_s_setprio(0);                                       \
    }

// ---------- main: 32 pairs/wave, B-frags in registers, ZERO loop barriers ------
__global__ __launch_bounds__(256, 3) void mlp_pairs_reg(
    const float* __restrict__ x,
    const float* __restrict__ W1, const float* __restrict__ b1,
    const ushort* __restrict__ WF,
    const float* __restrict__ b2, const float* __restrict__ W3,
    const float* __restrict__ b3, float* __restrict__ K)
{
    __shared__ __align__(16) float sa[MD], sc[MD], sb[MD];   // 12 KB total

    const int t = threadIdx.x;
    const int lane = t & 63;
    const int l15 = lane & 15, l4 = lane >> 4;
    const int wv = t >> 6;

    const float NL2E = -1.4426950408889634f;
    for (int m = t; m < MD; m += 256) {
        const float2 w = reinterpret_cast<const float2*>(W1)[m];
        sa[m] = w.x * NL2E;
        sc[m] = w.y * NL2E;
        sb[m] = b1[m] * NL2E;
    }

    const int pairbase = blockIdx.x * 128 + wv * 32;

    float xia[2], xja[2];
#pragma unroll
    for (int tm = 0; tm < 2; ++tm) {
        const int p = pairbase + tm * 16 + l15;
        if (p < NPAIR) {
            int i, j;
            ptoij(p, i, j);
            xia[tm] = x[i];
            xja[tm] = x[j];
        } else {
            xia[tm] = 0.f;
            xja[tm] = 0.f;
        }
    }

    f32x4 acc[2][8];
#pragma unroll
    for (int a = 0; a < 2; ++a)
#pragma unroll
        for (int b = 0; b < 8; ++b) acc[a][b] = (f32x4){0.f, 0.f, 0.f, 0.f};

    s16x8 bh[8];
    LOADB(0, 0);                     // issue chunk0/ks0 frag loads (global->reg)
    __syncthreads();                 // sa/sc/sb ready (the ONLY block barrier)

    s16x8 ah[2][2];
    for (int c = 0; c < 16; ++c) {
        SIG_CHUNK(c, ah);            // 640cy VALU: covers in-flight ks0 loads
        MFMA_HALF(0);                // consumes bh (vmcnt wait auto-inserted)
        LOADB(c, 1);                 // refill bh with ks1 frags
        MFMA_HALF(1);                // per-wave vmcnt stall; TLP covers (no barrier)
        if (c < 15) LOADB(c + 1, 0); // next chunk ks0 flies under next SIG
    }

    // epilogue: v = sum_k W3[k]*relu(h2 + b2[k]) + b3; reduce over 16 lanes (k)
    float w3v[8], b2v[8];
#pragma unroll
    for (int tn = 0; tn < 8; ++tn) {
        const int k = tn * 16 + l15;
        w3v[tn] = W3[k];
        b2v[tn] = b2[k];
    }
    const float b3v = b3[0];
#pragma unroll
    for (int tm = 0; tm < 2; ++tm)
#pragma unroll
        for (int r = 0; r < 4; ++r) {
            float v = 0.f;
#pragma unroll
            for (int tn = 0; tn < 8; ++tn)
                v = fmaf(w3v[tn], fmaxf(acc[tm][tn][r] + b2v[tn], 0.f), v);
            v += __shfl_xor(v, 1, 16);
            v += __shfl_xor(v, 2, 16);
            v += __shfl_xor(v, 4, 16);
            v += __shfl_xor(v, 8, 16);
            if (l15 == 0) {
                const int p = pairbase + tm * 16 + l4 * 4 + r;
                if (p < NPAIR) {
                    int i, j;
                    ptoij(p, i, j);
                    K[i * NN + j] = v + b3v;
                }
            }
        }
}

// ---------- fallback fp32 MLP kernel (only if ws too small; never expected) ----
#define MC 32
#define JT 128
#define SPAD 132
__global__ __launch_bounds__(256) void mlp_fill(
    const float* __restrict__ x,
    const float* __restrict__ W1, const float* __restrict__ b1,
    const float* __restrict__ W2, const float* __restrict__ b2,
    const float* __restrict__ W3, const float* __restrict__ b3,
    float* __restrict__ K)
{
    const int i  = blockIdx.y;
    const int j0 = blockIdx.x * JT;
    if (j0 + JT - 1 < i) return;
    __shared__ float sA[MD];
    __shared__ float sCw[MD];
    __shared__ float sxj[JT];
    __shared__ float S[MC][SPAD];
    __shared__ float W2t[MC][SPAD];
    const int t = threadIdx.x;
    const float xi = x[i];
    for (int m = t; m < MD; m += 256) {
        const float2 w = reinterpret_cast<const float2*>(W1)[m];
        sA[m]  = fmaf(xi, w.x, b1[m]);
        sCw[m] = w.y;
    }
    if (t < JT) sxj[t] = x[j0 + t];
    const int tk = t & 15;
    const int tj = t >> 4;
    float w3r[8], b2r[8];
#pragma unroll
    for (int kk = 0; kk < 8; kk++) {
        w3r[kk] = W3[tk * 8 + kk];
        b2r[kk] = b2[tk * 8 + kk];
    }
    float acc[8][8];
#pragma unroll
    for (int jj = 0; jj < 8; jj++)
#pragma unroll
        for (int kk = 0; kk < 8; kk++) acc[jj][kk] = 0.f;
    const int jx   = t & 127;
    const int mseg = (t >> 7) * 16;
    __syncthreads();
    const float xjv = sxj[jx];
    for (int m0 = 0; m0 < MD; m0 += MC) {
#pragma unroll
        for (int q = 0; q < 4; q++) {
            const int f   = t + q * 256;
            const int k   = f >> 3;
            const int mm4 = (f & 7) * 4;
            const float4 w = *reinterpret_cast<const float4*>(W2 + k * MD + m0 + mm4);
            W2t[mm4 + 0][k] = w.x;
            W2t[mm4 + 1][k] = w.y;
            W2t[mm4 + 2][k] = w.z;
            W2t[mm4 + 3][k] = w.w;
        }
#pragma unroll
        for (int q = 0; q < 16; q++) {
            const int ml = mseg + q;
            const float z = fmaf(xjv, sCw[m0 + ml], sA[m0 + ml]);
            S[ml][jx] = 1.0f / (1.0f + __expf(-z));
        }
        __syncthreads();
#pragma unroll 4
        for (int mm = 0; mm < MC; mm++) {
            const float4 s0 = *reinterpret_cast<const float4*>(&S[mm][tj * 8]);
            const float4 s1 = *reinterpret_cast<const float4*>(&S[mm][tj * 8 + 4]);
            const float4 w0 = *reinterpret_cast<const float4*>(&W2t[mm][tk * 8]);
            const float4 w1 = *reinterpret_cast<const float4*>(&W2t[mm][tk * 8 + 4]);
            const float sj[8] = {s0.x, s0.y, s0.z, s0.w, s1.x, s1.y, s1.z, s1.w};
            const float wk[8] = {w0.x, w0.y, w0.z, w0.w, w1.x, w1.y, w1.z, w1.w};
#pragma unroll
            for (int jj = 0; jj < 8; jj++)
#pragma unroll
                for (int kk = 0; kk < 8; kk++)
                    acc[jj][kk] = fmaf(sj[jj], wk[kk], acc[jj][kk]);
        }
        __syncthreads();
    }
    const float b3v = b3[0];
#pragma unroll
    for (int jj = 0; jj < 8; jj++) {
        float v = 0.f;
#pragma unroll
        for (int kk = 0; kk < 8; kk++) {
            const float h = acc[jj][kk] + b2r[kk];
            v = fmaf(w3r[kk], fmaxf(h, 0.f), v);
        }
#pragma unroll
        for (int off = 8; off >= 1; off >>= 1)
            v += __shfl_xor(v, off, 16);
        if (tk == 0) {
            const int j = j0 + tj * 8 + jj;
            if (j >= i) K[i * NN + j] = v + b3v;
        }
    }
}

// ---------- Kernel 2: C = K^T K, symmetric — compute upper tiles, mirror -------
__global__ __launch_bounds__(256) void ktk(const float* __restrict__ K,
                                           float* __restrict__ C)
{
    const int b0 = blockIdx.x * 64;
    const int a0 = blockIdx.y * 64;
    if (b0 < a0) return;             // C symmetric: only tiles with b0 >= a0
    __shared__ float Ka[64][68];
    __shared__ float Kb[64][68];
    const int t  = threadIdx.x;
    const int tb = t & 15;
    const int ta = t >> 4;
    float acc[4][4];
#pragma unroll
    for (int u = 0; u < 4; u++)
#pragma unroll
        for (int v = 0; v < 4; v++) acc[u][v] = 0.f;
    const int kmax = a0 + 64;        // K[k][a]=0 for k>a; a0 <= b0
    for (int k0 = 0; k0 < kmax; k0 += 64) {
#pragma unroll
        for (int q = 0; q < 4; q++) {
            const int f  = t + q * 256;
            const int kk = f >> 4;
            const int c4 = (f & 15) * 4;
            *reinterpret_cast<float4*>(&Ka[kk][c4]) =
                *reinterpret_cast<const float4*>(K + (k0 + kk) * NN + a0 + c4);
            *reinterpret_cast<float4*>(&Kb[kk][c4]) =
                *reinterpret_cast<const float4*>(K + (k0 + kk) * NN + b0 + c4);
        }
        __syncthreads();
#pragma unroll 8
        for (int kk = 0; kk < 64; kk++) {
            const float4 av = *reinterpret_cast<const float4*>(&Ka[kk][ta * 4]);
            const float4 bv = *reinterpret_cast<const float4*>(&Kb[kk][tb * 4]);
            const float a4[4] = {av.x, av.y, av.z, av.w};
            const float b4[4] = {bv.x, bv.y, bv.z, bv.w};
#pragma unroll
            for (int u = 0; u < 4; u++)
#pragma unroll
                for (int v = 0; v < 4; v++)
                    acc[u][v] = fmaf(a4[u], b4[v], acc[u][v]);
        }
        __syncthreads();
    }
#pragma unroll
    for (int u = 0; u < 4; u++) {
        float4 o;
        o.x = acc[u][0]; o.y = acc[u][1]; o.z = acc[u][2]; o.w = acc[u][3];
        *reinterpret_cast<float4*>(C + (a0 + ta * 4 + u) * NN + b0 + tb * 4) = o;
    }
    if (b0 > a0) {                   // mirror tile: C[b][a] = C[a][b], coalesced
#pragma unroll
        for (int v = 0; v < 4; v++) {
            float4 o;
            o.x = acc[0][v]; o.y = acc[1][v]; o.z = acc[2][v]; o.w = acc[3][v];
            *reinterpret_cast<float4*>(C + (b0 + tb * 4 + v) * NN + a0 + ta * 4) = o;
        }
    }
}

extern "C" void kernel_launch(void* const* d_in, const int* in_sizes, int n_in,
                              void* d_out, int out_size, void* d_ws, size_t ws_size,
                              hipStream_t stream)
{
    const float* x  = (const float*)d_in[0];
    const float* W1 = (const float*)d_in[1];
    const float* b1 = (const float*)d_in[2];
    const float* W2 = (const float*)d_in[3];
    const float* b2 = (const float*)d_in[4];
    const float* W3 = (const float*)d_in[5];
    const float* b3 = (const float*)d_in[6];
    float* Kmat = (float*)d_ws;                       // 2,359,296 B
    float* C    = (float*)d_out;

    const size_t kBytes = (size_t)NN * NN * sizeof(float);
    const size_t need   = kBytes + 262144;            // + W2 bf16 frag-major

    hipMemsetAsync(Kmat, 0, kBytes, stream);
    if (ws_size >= need) {
        ushort* WF = (ushort*)((char*)d_ws + kBytes);
        w2frag<<<64, 256, 0, stream>>>(W2, WF);
        mlp_pairs_reg<<<NPBLK2, 256, 0, stream>>>(x, W1, b1, WF, b2, W3, b3, Kmat);
    } else {
        mlp_fill<<<dim3(6, NN), 256, 0, stream>>>(x, W1, b1, W2, b2, W3, b3, Kmat);
    }
    ktk<<<dim3(NN / 64, NN / 64), 256, 0, stream>>>(Kmat, C);
}